// Round 5
// baseline (553.320 us; speedup 1.0000x reference)
//
#include <hip/hip_runtime.h>
#include <math.h>

#define N_NODES 100000
#define N_EDGES 3200000
#define F_IN    37
#define H_DIM   16
#define C_DIM   2

#define BUCKET_BITS 7
#define BUCKET_SZ   128
#define NBUCK       782          // ceil(100000/128)
#define CAP         4608         // bucket capacity: mean 4092 + 8 sigma
#define CHUNK       4096
#define NCHUNK      782          // ceil(3.2M/4096)
#define EPT         4
#define ASTRIDE     17           // padded per-node LDS stride (floats)

// ---------- init bucket cursors ----------
__global__ void k_init(int* __restrict__ gcur) {
    int i = blockIdx.x * blockDim.x + threadIdx.x;
    if (i < NBUCK) gcur[i] = i * CAP;
}

// ---------- partition edges into destination buckets ----------
// packed: (row | col_local<<17, w)
__global__ __launch_bounds__(1024) void k_part(
    const int* __restrict__ row, const int* __restrict__ col,
    const float* __restrict__ w, int* __restrict__ gcur, int2* __restrict__ ebuf)
{
    __shared__ int cnt[NBUCK];
    __shared__ int gbase[NBUCK];
    int t = threadIdx.x;
    int e0 = blockIdx.x * CHUNK;
    int bk[EPT], rc[EPT], lofs[EPT];
    float wv[EPT];

    if (t < NBUCK) cnt[t] = 0;
    __syncthreads();
#pragma unroll
    for (int k = 0; k < EPT; k++) {
        int e = e0 + k * 1024 + t;
        if (e < N_EDGES) {
            int r = row[e], c = col[e];
            wv[k] = w[e];
            bk[k] = c >> BUCKET_BITS;
            rc[k] = r | ((c & (BUCKET_SZ - 1)) << 17);
            lofs[k] = atomicAdd(&cnt[bk[k]], 1);
        } else bk[k] = -1;
    }
    __syncthreads();
    if (t < NBUCK) gbase[t] = atomicAdd(&gcur[t], cnt[t]);
    __syncthreads();
#pragma unroll
    for (int k = 0; k < EPT; k++) {
        if (bk[k] >= 0)
            ebuf[gbase[bk[k]] + lofs[k]] = make_int2(rc[k], __float_as_int(wv[k]));
    }
}

// ---------- per-bucket degree from partitioned edges -> dinv ----------
__global__ __launch_bounds__(256) void k_deg_seg(
    const int* __restrict__ gcur, const int2* __restrict__ ebuf,
    float* __restrict__ dinv)
{
    __shared__ float dsum[BUCKET_SZ];
    int t = threadIdx.x, b = blockIdx.x;
    if (t < BUCKET_SZ) dsum[t] = 0.f;
    __syncthreads();
    int s = b * CAP, e = gcur[b];
    int len = e - s;
    int nb = len & ~1023;                      // batches of 1024 (256 thr x 4)
    for (int off = t << 2; off < nb; off += 1024) {
        int2 v0 = ebuf[s + off + 0];
        int2 v1 = ebuf[s + off + 1];
        int2 v2 = ebuf[s + off + 2];
        int2 v3 = ebuf[s + off + 3];
        atomicAdd(&dsum[v0.x >> 17], __int_as_float(v0.y));
        atomicAdd(&dsum[v1.x >> 17], __int_as_float(v1.y));
        atomicAdd(&dsum[v2.x >> 17], __int_as_float(v2.y));
        atomicAdd(&dsum[v3.x >> 17], __int_as_float(v3.y));
    }
    for (int p = s + nb + t; p < e; p += 256) {
        int2 v = ebuf[p];
        atomicAdd(&dsum[v.x >> 17], __int_as_float(v.y));
    }
    __syncthreads();
    int c = (b << BUCKET_BITS) + t;
    if (t < BUCKET_SZ && c < N_NODES) dinv[c] = rsqrtf(dsum[t] + 1.0f);
}

// ---------- h1s = dinv * (x @ W1), x staged via LDS ----------
__global__ __launch_bounds__(256) void k_xw1(
    const float* __restrict__ x, const float* __restrict__ W1,
    const float* __restrict__ dinv, float* __restrict__ h1s)
{
    __shared__ float xs[256 * F_IN];          // 37.9 KB
    __shared__ float sW[F_IN * H_DIM];
    int t = threadIdx.x;
    int nb = blockIdx.x * 256;
    for (int idx = t; idx < F_IN * H_DIM; idx += 256) sW[idx] = W1[idx];
    int g0 = nb * F_IN;
    for (int idx = t; idx < 256 * F_IN; idx += 256) {
        int gi = g0 + idx;
        if (gi < N_NODES * F_IN) xs[idx] = x[gi];
    }
    __syncthreads();
    int i = nb + t;
    if (i >= N_NODES) return;
    float acc[H_DIM];
#pragma unroll
    for (int j = 0; j < H_DIM; j++) acc[j] = 0.f;
    const float* xi = &xs[t * F_IN];
    for (int k = 0; k < F_IN; k++) {
        float xv = xi[k];
#pragma unroll
        for (int j = 0; j < H_DIM; j++) acc[j] += xv * sW[k * H_DIM + j];
    }
    float di = dinv[i];
    float4* o = (float4*)(h1s + (size_t)i * H_DIM);
#pragma unroll
    for (int j = 0; j < 4; j++)
        o[j] = make_float4(di * acc[j * 4 + 0], di * acc[j * 4 + 1],
                           di * acc[j * 4 + 2], di * acc[j * 4 + 3]);
}

// ---------- layer 1: thread-per-edge, full-row gather, LDS accumulate,
//            fused relu/bias + @W2 -> h2s ----------
__global__ __launch_bounds__(1024) void k_agg1(
    const int* __restrict__ gcur, const int2* __restrict__ ebuf,
    const float* __restrict__ h1s, const float* __restrict__ dinv,
    const float* __restrict__ b1, const float* __restrict__ W2,
    float* __restrict__ h2s)
{
    __shared__ float acc[BUCKET_SZ * ASTRIDE];   // 8.5 KB
    __shared__ float sW2[H_DIM * C_DIM];
    __shared__ float sb1[H_DIM];
    int t = threadIdx.x, b = blockIdx.x;
    int nbase = b << BUCKET_BITS;
    for (int i = t; i < BUCKET_SZ * ASTRIDE; i += 1024) acc[i] = 0.f;
    if (t < H_DIM * C_DIM) sW2[t] = W2[t];
    if (t >= 64 && t < 64 + H_DIM) sb1[t - 64] = b1[t - 64];
    __syncthreads();

    int s = b * CAP, e = gcur[b];
    const float4* h14 = (const float4*)h1s;
    for (int p = s + t; p < e; p += 1024) {
        int2 v = ebuf[p];
        float a = __int_as_float(v.y);
        int r  = v.x & 0x1FFFF;
        int cl = v.x >> 17;
        const float4* hr = &h14[(size_t)r * 4];
        float4 g0 = hr[0];                      // 4 independent 16B loads,
        float4 g1 = hr[1];                      // one 64B line per lane
        float4 g2 = hr[2];
        float4 g3 = hr[3];
        float* ap = &acc[cl * ASTRIDE];
        atomicAdd(ap +  0, a * g0.x); atomicAdd(ap +  1, a * g0.y);
        atomicAdd(ap +  2, a * g0.z); atomicAdd(ap +  3, a * g0.w);
        atomicAdd(ap +  4, a * g1.x); atomicAdd(ap +  5, a * g1.y);
        atomicAdd(ap +  6, a * g1.z); atomicAdd(ap +  7, a * g1.w);
        atomicAdd(ap +  8, a * g2.x); atomicAdd(ap +  9, a * g2.y);
        atomicAdd(ap + 10, a * g2.z); atomicAdd(ap + 11, a * g2.w);
        atomicAdd(ap + 12, a * g3.x); atomicAdd(ap + 13, a * g3.y);
        atomicAdd(ap + 14, a * g3.z); atomicAdd(ap + 15, a * g3.w);
    }
    __syncthreads();

    // epilogue: 128 nodes x 4 quad-lanes = 512 active threads
    if (t < BUCKET_SZ * 4) {
        int n = t >> 2, q = t & 3;
        int c = nbase + n;
        float p0 = 0.f, p1 = 0.f, dc = 0.f;
        if (c < N_NODES) {
            dc = dinv[c];
            const float* ap = &acc[n * ASTRIDE + (q << 2)];
            float4 hc = h14[(size_t)c * 4 + q];
            int j0 = q << 2;
            float hcv[4] = {hc.x, hc.y, hc.z, hc.w};
#pragma unroll
            for (int j = 0; j < 4; j++) {
                float rv = fmaxf(dc * (ap[j] + hcv[j]) + sb1[j0 + j], 0.f);
                p0 += rv * sW2[(j0 + j) * C_DIM + 0];
                p1 += rv * sW2[(j0 + j) * C_DIM + 1];
            }
        }
        p0 += __shfl_xor(p0, 1); p0 += __shfl_xor(p0, 2);
        p1 += __shfl_xor(p1, 1); p1 += __shfl_xor(p1, 2);
        if (q == 0 && c < N_NODES) ((float2*)h2s)[c] = make_float2(dc * p0, dc * p1);
    }
}

// ---------- layer 2: batched x4, LDS accumulate + bias + log_softmax ----------
__global__ __launch_bounds__(256) void k_agg2(
    const int* __restrict__ gcur, const int2* __restrict__ ebuf,
    const float* __restrict__ h2s, const float* __restrict__ dinv,
    const float* __restrict__ b2, float* __restrict__ out)
{
    __shared__ float acc[BUCKET_SZ * 2];
    int t = threadIdx.x, b = blockIdx.x;
    int nbase = b << BUCKET_BITS;
    if (t < BUCKET_SZ * 2) acc[t] = 0.f;
    __syncthreads();
    int s = b * CAP, e = gcur[b];
    const float2* h22 = (const float2*)h2s;
    int len = e - s;
    int nb = len & ~1023;
    for (int off = t << 2; off < nb; off += 1024) {
        int2 v0 = ebuf[s + off + 0];
        int2 v1 = ebuf[s + off + 1];
        int2 v2 = ebuf[s + off + 2];
        int2 v3 = ebuf[s + off + 3];
        float2 g0 = h22[v0.x & 0x1FFFF];
        float2 g1 = h22[v1.x & 0x1FFFF];
        float2 g2 = h22[v2.x & 0x1FFFF];
        float2 g3 = h22[v3.x & 0x1FFFF];
        atomicAdd(&acc[(v0.x >> 17) * 2 + 0], __int_as_float(v0.y) * g0.x);
        atomicAdd(&acc[(v0.x >> 17) * 2 + 1], __int_as_float(v0.y) * g0.y);
        atomicAdd(&acc[(v1.x >> 17) * 2 + 0], __int_as_float(v1.y) * g1.x);
        atomicAdd(&acc[(v1.x >> 17) * 2 + 1], __int_as_float(v1.y) * g1.y);
        atomicAdd(&acc[(v2.x >> 17) * 2 + 0], __int_as_float(v2.y) * g2.x);
        atomicAdd(&acc[(v2.x >> 17) * 2 + 1], __int_as_float(v2.y) * g2.y);
        atomicAdd(&acc[(v3.x >> 17) * 2 + 0], __int_as_float(v3.y) * g3.x);
        atomicAdd(&acc[(v3.x >> 17) * 2 + 1], __int_as_float(v3.y) * g3.y);
    }
    for (int p = s + nb + t; p < e; p += 256) {
        int2 v = ebuf[p];
        float2 g = h22[v.x & 0x1FFFF];
        atomicAdd(&acc[(v.x >> 17) * 2 + 0], __int_as_float(v.y) * g.x);
        atomicAdd(&acc[(v.x >> 17) * 2 + 1], __int_as_float(v.y) * g.y);
    }
    __syncthreads();
    int c = nbase + t;
    if (t < BUCKET_SZ && c < N_NODES) {
        float dc = dinv[c];
        float2 hc = h22[c];
        float l0 = dc * (acc[t * 2 + 0] + hc.x) + b2[0];
        float l1 = dc * (acc[t * 2 + 1] + hc.y) + b2[1];
        float m = fmaxf(l0, l1);
        float lse = m + logf(expf(l0 - m) + expf(l1 - m));
        ((float2*)out)[c] = make_float2(l0 - lse, l1 - lse);
    }
}

extern "C" void kernel_launch(void* const* d_in, const int* in_sizes, int n_in,
                              void* d_out, int out_size, void* d_ws, size_t ws_size,
                              hipStream_t stream) {
    const float* x  = (const float*)d_in[0];
    const int*   ei = (const int*)d_in[1];     // [2, E]: row then col
    const float* w  = (const float*)d_in[2];
    const float* W1 = (const float*)d_in[3];
    const float* b1 = (const float*)d_in[4];
    const float* W2 = (const float*)d_in[5];
    const float* b2 = (const float*)d_in[6];
    float* out = (float*)d_out;

    const int* row = ei;
    const int* col = ei + N_EDGES;

    // workspace layout
    char* ws = (char*)d_ws;
    int*   gcur = (int*)(ws + 0);                //     3,200 B
    int2*  ebuf = (int2*)(ws + 3200);            //28,827,648 B (782*4608*8)
    float* dinv = (float*)(ws + 28830848);       //   400,000 B
    float* h1s  = (float*)(ws + 29230848);       // 6,400,000 B
    float* h2s  = (float*)(ws + 35630848);       //   800,000 B
    // end: 36,430,848 B

    k_init   <<<4, 256, 0, stream>>>(gcur);
    k_part   <<<NCHUNK, 1024, 0, stream>>>(row, col, w, gcur, ebuf);
    k_deg_seg<<<NBUCK, 256, 0, stream>>>(gcur, ebuf, dinv);
    k_xw1    <<<(N_NODES + 255) / 256, 256, 0, stream>>>(x, W1, dinv, h1s);
    k_agg1   <<<NBUCK, 1024, 0, stream>>>(gcur, ebuf, h1s, dinv, b1, W2, h2s);
    k_agg2   <<<NBUCK, 256, 0, stream>>>(gcur, ebuf, h2s, dinv, b2, out);
}

// Round 6
// 282.867 us; speedup vs baseline: 1.9561x; 1.9561x over previous
//
#include <hip/hip_runtime.h>
#include <math.h>

#define N_NODES 100000
#define N_EDGES 3200000
#define F_IN    37
#define H_DIM   16
#define C_DIM   2

#define BUCKET_BITS 7
#define BUCKET_SZ   128
#define NBUCK       782          // ceil(100000/128)
#define CAP         4736         // bucket capacity: mean 4092 + 10 sigma
#define CHUNK       4096
#define NCHUNK      782          // ceil(3.2M/4096)
#define EPT         4
#define EPT_S       5            // ceil(CAP/1024)

// ---------- init bucket cursors ----------
__global__ void k_init(int* __restrict__ gcur) {
    int i = blockIdx.x * blockDim.x + threadIdx.x;
    if (i < NBUCK) gcur[i] = i * CAP;
}

// ---------- partition edges into destination buckets ----------
// packed: (row | col_local<<17, w)
__global__ __launch_bounds__(1024) void k_part(
    const int* __restrict__ row, const int* __restrict__ col,
    const float* __restrict__ w, int* __restrict__ gcur, int2* __restrict__ ebuf)
{
    __shared__ int cnt[NBUCK];
    __shared__ int gbase[NBUCK];
    int t = threadIdx.x;
    int e0 = blockIdx.x * CHUNK;
    int bk[EPT], rc[EPT], lofs[EPT];
    float wv[EPT];

    if (t < NBUCK) cnt[t] = 0;
    __syncthreads();
#pragma unroll
    for (int k = 0; k < EPT; k++) {
        int e = e0 + k * 1024 + t;
        if (e < N_EDGES) {
            int r = row[e], c = col[e];
            wv[k] = w[e];
            bk[k] = c >> BUCKET_BITS;
            rc[k] = r | ((c & (BUCKET_SZ - 1)) << 17);
            lofs[k] = atomicAdd(&cnt[bk[k]], 1);
        } else bk[k] = -1;
    }
    __syncthreads();
    if (t < NBUCK) gbase[t] = atomicAdd(&gcur[t], cnt[t]);
    __syncthreads();
#pragma unroll
    for (int k = 0; k < EPT; k++) {
        if (bk[k] >= 0)
            ebuf[gbase[bk[k]] + lofs[k]] = make_int2(rc[k], __float_as_int(wv[k]));
    }
}

// ---------- per-bucket counting sort (in place) -> CSR rp + dinv ----------
__global__ __launch_bounds__(1024) void k_sort(
    const int* __restrict__ gcur, int2* __restrict__ ebuf,
    int2* __restrict__ rp, float* __restrict__ dinv)
{
    __shared__ int   cnt[BUCKET_SZ];
    __shared__ int   base[BUCKET_SZ];
    __shared__ float wsum[BUCKET_SZ];
    int t = threadIdx.x, b = blockIdx.x;
    int s = b * CAP;
    int len = gcur[b] - s;
    if (t < BUCKET_SZ) { cnt[t] = 0; wsum[t] = 0.f; }
    __syncthreads();

    int2 ed[EPT_S]; int cl[EPT_S], lofs[EPT_S];
#pragma unroll
    for (int k = 0; k < EPT_S; k++) {
        int i = k * 1024 + t;
        if (i < len) {
            int2 v = ebuf[s + i];
            ed[k] = v;
            cl[k] = v.x >> 17;
            lofs[k] = atomicAdd(&cnt[cl[k]], 1);
            atomicAdd(&wsum[cl[k]], __int_as_float(v.y));
        } else cl[k] = -1;
    }
    __syncthreads();
    // inclusive scan of cnt[128] in LDS
    if (t < BUCKET_SZ) base[t] = cnt[t];
    __syncthreads();
    for (int off = 1; off < BUCKET_SZ; off <<= 1) {
        int v2 = 0;
        if (t < BUCKET_SZ && t >= off) v2 = base[t - off];
        __syncthreads();
        if (t < BUCKET_SZ) base[t] += v2;
        __syncthreads();
    }
    // scatter back in node-sorted order (all reads completed before here)
#pragma unroll
    for (int k = 0; k < EPT_S; k++) {
        if (cl[k] >= 0) {
            int pos = base[cl[k]] - cnt[cl[k]] + lofs[k];
            ebuf[s + pos] = ed[k];
        }
    }
    int c = (b << BUCKET_BITS) + t;
    if (t < BUCKET_SZ && c < N_NODES) {
        rp[c] = make_int2(s + base[t] - cnt[t], cnt[t]);
        dinv[c] = rsqrtf(wsum[t] + 1.0f);
    }
}

// ---------- h1s = dinv * (x @ W1), x staged via LDS ----------
__global__ __launch_bounds__(256) void k_xw1(
    const float* __restrict__ x, const float* __restrict__ W1,
    const float* __restrict__ dinv, float* __restrict__ h1s)
{
    __shared__ float xs[256 * F_IN];          // 37.9 KB
    __shared__ float sW[F_IN * H_DIM];
    int t = threadIdx.x;
    int nb = blockIdx.x * 256;
    for (int idx = t; idx < F_IN * H_DIM; idx += 256) sW[idx] = W1[idx];
    int g0 = nb * F_IN;
    for (int idx = t; idx < 256 * F_IN; idx += 256) {
        int gi = g0 + idx;
        if (gi < N_NODES * F_IN) xs[idx] = x[gi];
    }
    __syncthreads();
    int i = nb + t;
    if (i >= N_NODES) return;
    float acc[H_DIM];
#pragma unroll
    for (int j = 0; j < H_DIM; j++) acc[j] = 0.f;
    const float* xi = &xs[t * F_IN];
    for (int k = 0; k < F_IN; k++) {
        float xv = xi[k];
#pragma unroll
        for (int j = 0; j < H_DIM; j++) acc[j] += xv * sW[k * H_DIM + j];
    }
    float di = dinv[i];
    float4* o = (float4*)(h1s + (size_t)i * H_DIM);
#pragma unroll
    for (int j = 0; j < 4; j++)
        o[j] = make_float4(di * acc[j * 4 + 0], di * acc[j * 4 + 1],
                           di * acc[j * 4 + 2], di * acc[j * 4 + 3]);
}

// ---------- layer 1: CSR register-accumulate (no atomics),
//            fused relu/bias + @W2 -> h2s ----------
__global__ __launch_bounds__(256) void k_agg1(
    const int2* __restrict__ rp, const int2* __restrict__ ebuf,
    const float* __restrict__ h1s, const float* __restrict__ dinv,
    const float* __restrict__ b1, const float* __restrict__ W2,
    float* __restrict__ h2s)
{
    __shared__ float sW2[H_DIM * C_DIM];
    __shared__ float sb1[H_DIM];
    int t = threadIdx.x;
    if (t < H_DIM * C_DIM) sW2[t] = W2[t];
    if (t >= 32 && t < 32 + H_DIM) sb1[t - 32] = b1[t - 32];
    __syncthreads();
    int id = blockIdx.x * 256 + t;
    int c = id >> 2, q = id & 3;
    if (c >= N_NODES) return;
    int2 seg = rp[c];
    int s = seg.x, n = seg.y;
    const float4* h14 = (const float4*)h1s;
    float4 acc = make_float4(0.f, 0.f, 0.f, 0.f);
    int2 v;
    if (n > 0) v = ebuf[s];
    for (int i = 0; i < n; i++) {
        int2 cur = v;
        if (i + 1 < n) v = ebuf[s + i + 1];
        float a = __int_as_float(cur.y);
        int r = cur.x & 0x1FFFF;
        float4 hv = h14[(size_t)r * 4 + q];
        acc.x += a * hv.x; acc.y += a * hv.y;
        acc.z += a * hv.z; acc.w += a * hv.w;
    }
    float dc = dinv[c];
    float4 hc = h14[(size_t)c * 4 + q];
    int j0 = q << 2;
    float av[4] = {acc.x + hc.x, acc.y + hc.y, acc.z + hc.z, acc.w + hc.w};
    float p0 = 0.f, p1 = 0.f;
#pragma unroll
    for (int j = 0; j < 4; j++) {
        float rv = fmaxf(dc * av[j] + sb1[j0 + j], 0.f);
        p0 += rv * sW2[(j0 + j) * C_DIM + 0];
        p1 += rv * sW2[(j0 + j) * C_DIM + 1];
    }
    p0 += __shfl_xor(p0, 1); p0 += __shfl_xor(p0, 2);
    p1 += __shfl_xor(p1, 1); p1 += __shfl_xor(p1, 2);
    if (q == 0) ((float2*)h2s)[c] = make_float2(dc * p0, dc * p1);
}

// ---------- layer 2: CSR register-accumulate + bias + log_softmax ----------
__global__ __launch_bounds__(256) void k_agg2(
    const int2* __restrict__ rp, const int2* __restrict__ ebuf,
    const float* __restrict__ h2s, const float* __restrict__ dinv,
    const float* __restrict__ b2, float* __restrict__ out)
{
    int c = blockIdx.x * 256 + threadIdx.x;
    if (c >= N_NODES) return;
    int2 seg = rp[c];
    int s = seg.x, n = seg.y;
    const float2* h22 = (const float2*)h2s;
    float a0 = 0.f, a1 = 0.f;
    int2 v;
    if (n > 0) v = ebuf[s];
    for (int i = 0; i < n; i++) {
        int2 cur = v;
        if (i + 1 < n) v = ebuf[s + i + 1];
        float a = __int_as_float(cur.y);
        float2 hv = h22[cur.x & 0x1FFFF];
        a0 += a * hv.x;
        a1 += a * hv.y;
    }
    float dc = dinv[c];
    float2 hc = h22[c];
    float l0 = dc * (a0 + hc.x) + b2[0];
    float l1 = dc * (a1 + hc.y) + b2[1];
    float m = fmaxf(l0, l1);
    float lse = m + logf(expf(l0 - m) + expf(l1 - m));
    ((float2*)out)[c] = make_float2(l0 - lse, l1 - lse);
}

extern "C" void kernel_launch(void* const* d_in, const int* in_sizes, int n_in,
                              void* d_out, int out_size, void* d_ws, size_t ws_size,
                              hipStream_t stream) {
    const float* x  = (const float*)d_in[0];
    const int*   ei = (const int*)d_in[1];     // [2, E]: row then col
    const float* w  = (const float*)d_in[2];
    const float* W1 = (const float*)d_in[3];
    const float* b1 = (const float*)d_in[4];
    const float* W2 = (const float*)d_in[5];
    const float* b2 = (const float*)d_in[6];
    float* out = (float*)d_out;

    const int* row = ei;
    const int* col = ei + N_EDGES;

    // workspace layout (64B-aligned offsets)
    char* ws = (char*)d_ws;
    int*   gcur = (int*)(ws + 0);                //     3,200 B
    int2*  rp   = (int2*)(ws + 3200);            //   800,000 B (start,count per node)
    float* dinv = (float*)(ws + 803200);         //   400,000 B
    float* h1s  = (float*)(ws + 1203200);        // 6,400,000 B
    float* h2s  = (float*)(ws + 7603200);        //   800,000 B
    int2*  ebuf = (int2*)(ws + 8403200);         //29,628,416 B (782*4736*8)
    // end: 38,031,616 B

    k_init <<<4, 256, 0, stream>>>(gcur);
    k_part <<<NCHUNK, 1024, 0, stream>>>(row, col, w, gcur, ebuf);
    k_sort <<<NBUCK, 1024, 0, stream>>>(gcur, ebuf, rp, dinv);
    k_xw1  <<<(N_NODES + 255) / 256, 256, 0, stream>>>(x, W1, dinv, h1s);
    k_agg1 <<<(4 * N_NODES + 255) / 256, 256, 0, stream>>>(rp, ebuf, h1s, dinv, b1, W2, h2s);
    k_agg2 <<<(N_NODES + 255) / 256, 256, 0, stream>>>(rp, ebuf, h2s, dinv, b2, out);
}

// Round 7
// 266.233 us; speedup vs baseline: 2.0783x; 1.0625x over previous
//
#include <hip/hip_runtime.h>
#include <math.h>

#define N_NODES 100000
#define N_EDGES 3200000
#define F_IN    37
#define H_DIM   16
#define C_DIM   2

#define BUCKET_BITS 7
#define BUCKET_SZ   128
#define NBUCK       782          // ceil(100000/128)
#define CAP         4736         // bucket capacity: mean 4092 + 10 sigma
#define CHUNK       8192
#define NCHUNK      391          // ceil(3.2M/8192)
#define EPT         8
#define EPT_S       5            // ceil(CAP/1024)

__device__ __forceinline__ unsigned bf16rne(float f) {
    unsigned u = __float_as_uint(f);
    return (u + 0x7FFFu + ((u >> 16) & 1u)) >> 16;
}

// ---------- init bucket cursors ----------
__global__ void k_init(int* __restrict__ gcur) {
    int i = blockIdx.x * blockDim.x + threadIdx.x;
    if (i < NBUCK) gcur[i] = i * CAP;
}

// ---------- partition edges into destination buckets ----------
// packed: (row | col_local<<17, w)
__global__ __launch_bounds__(1024) void k_part(
    const int* __restrict__ row, const int* __restrict__ col,
    const float* __restrict__ w, int* __restrict__ gcur, int2* __restrict__ ebuf)
{
    __shared__ int cnt[NBUCK];
    __shared__ int gbase[NBUCK];
    int t = threadIdx.x;
    int e0 = blockIdx.x * CHUNK;
    int bk[EPT], rc[EPT], lofs[EPT];
    float wv[EPT];

    if (t < NBUCK) cnt[t] = 0;
    __syncthreads();
#pragma unroll
    for (int k = 0; k < EPT; k++) {
        int e = e0 + k * 1024 + t;
        if (e < N_EDGES) {
            int r = row[e], c = col[e];
            wv[k] = w[e];
            bk[k] = c >> BUCKET_BITS;
            rc[k] = r | ((c & (BUCKET_SZ - 1)) << 17);
            lofs[k] = atomicAdd(&cnt[bk[k]], 1);
        } else bk[k] = -1;
    }
    __syncthreads();
    if (t < NBUCK) gbase[t] = atomicAdd(&gcur[t], cnt[t]);
    __syncthreads();
#pragma unroll
    for (int k = 0; k < EPT; k++) {
        if (bk[k] >= 0)
            ebuf[gbase[bk[k]] + lofs[k]] = make_int2(rc[k], __float_as_int(wv[k]));
    }
}

// ---------- per-bucket counting sort (in place) -> CSR rp + dinv ----------
__global__ __launch_bounds__(1024) void k_sort(
    const int* __restrict__ gcur, int2* __restrict__ ebuf,
    int2* __restrict__ rp, float* __restrict__ dinv)
{
    __shared__ int   cnt[BUCKET_SZ];
    __shared__ int   base[BUCKET_SZ];
    __shared__ float wsum[BUCKET_SZ];
    int t = threadIdx.x, b = blockIdx.x;
    int s = b * CAP;
    int len = gcur[b] - s;
    if (t < BUCKET_SZ) { cnt[t] = 0; wsum[t] = 0.f; }
    __syncthreads();

    int2 ed[EPT_S]; int cl[EPT_S], lofs[EPT_S];
#pragma unroll
    for (int k = 0; k < EPT_S; k++) {
        int i = k * 1024 + t;
        if (i < len) {
            int2 v = ebuf[s + i];
            ed[k] = v;
            cl[k] = v.x >> 17;
            lofs[k] = atomicAdd(&cnt[cl[k]], 1);
            atomicAdd(&wsum[cl[k]], __int_as_float(v.y));
        } else cl[k] = -1;
    }
    __syncthreads();
    // inclusive scan of cnt[128] in LDS
    if (t < BUCKET_SZ) base[t] = cnt[t];
    __syncthreads();
    for (int off = 1; off < BUCKET_SZ; off <<= 1) {
        int v2 = 0;
        if (t < BUCKET_SZ && t >= off) v2 = base[t - off];
        __syncthreads();
        if (t < BUCKET_SZ) base[t] += v2;
        __syncthreads();
    }
    // scatter back in node-sorted order
#pragma unroll
    for (int k = 0; k < EPT_S; k++) {
        if (cl[k] >= 0) {
            int pos = base[cl[k]] - cnt[cl[k]] + lofs[k];
            ebuf[s + pos] = ed[k];
        }
    }
    int c = (b << BUCKET_BITS) + t;
    if (t < BUCKET_SZ && c < N_NODES) {
        rp[c] = make_int2(s + base[t] - cnt[t], cnt[t]);
        dinv[c] = rsqrtf(wsum[t] + 1.0f);
    }
}

// ---------- h1b = bf16(dinv * (x @ W1)), x staged via LDS ----------
__global__ __launch_bounds__(256) void k_xw1(
    const float* __restrict__ x, const float* __restrict__ W1,
    const float* __restrict__ dinv, uint4* __restrict__ h1b)
{
    __shared__ float xs[256 * F_IN];          // 37.9 KB
    __shared__ float sW[F_IN * H_DIM];
    int t = threadIdx.x;
    int nb = blockIdx.x * 256;
    for (int idx = t; idx < F_IN * H_DIM; idx += 256) sW[idx] = W1[idx];
    int g0 = nb * F_IN;
    for (int idx = t; idx < 256 * F_IN; idx += 256) {
        int gi = g0 + idx;
        if (gi < N_NODES * F_IN) xs[idx] = x[gi];
    }
    __syncthreads();
    int i = nb + t;
    if (i >= N_NODES) return;
    float acc[H_DIM];
#pragma unroll
    for (int j = 0; j < H_DIM; j++) acc[j] = 0.f;
    const float* xi = &xs[t * F_IN];
    for (int k = 0; k < F_IN; k++) {
        float xv = xi[k];
#pragma unroll
        for (int j = 0; j < H_DIM; j++) acc[j] += xv * sW[k * H_DIM + j];
    }
    float di = dinv[i];
    unsigned p[8];
#pragma unroll
    for (int j = 0; j < 8; j++) {
        unsigned lo = bf16rne(di * acc[2 * j]);
        unsigned hi = bf16rne(di * acc[2 * j + 1]);
        p[j] = lo | (hi << 16);
    }
    h1b[(size_t)i * 2 + 0] = make_uint4(p[0], p[1], p[2], p[3]);
    h1b[(size_t)i * 2 + 1] = make_uint4(p[4], p[5], p[6], p[7]);
}

// ---------- layer 1: CSR register-accumulate over bf16 h1 rows (32B),
//            fused relu/bias + @W2 -> h2s ----------
__global__ __launch_bounds__(256) void k_agg1(
    const int2* __restrict__ rp, const int2* __restrict__ ebuf,
    const uint2* __restrict__ h1b, const float* __restrict__ dinv,
    const float* __restrict__ b1, const float* __restrict__ W2,
    float* __restrict__ h2s)
{
    __shared__ float sW2[H_DIM * C_DIM];
    __shared__ float sb1[H_DIM];
    int t = threadIdx.x;
    if (t < H_DIM * C_DIM) sW2[t] = W2[t];
    if (t >= 32 && t < 32 + H_DIM) sb1[t - 32] = b1[t - 32];
    __syncthreads();
    int id = blockIdx.x * 256 + t;
    int c = id >> 2, q = id & 3;
    if (c >= N_NODES) return;
    int2 seg = rp[c];
    int s = seg.x, n = seg.y;
    float4 acc = make_float4(0.f, 0.f, 0.f, 0.f);
    int2 v;
    if (n > 0) v = ebuf[s];
    for (int i = 0; i < n; i++) {
        int2 cur = v;
        if (i + 1 < n) v = ebuf[s + i + 1];
        float a = __int_as_float(cur.y);
        int r = cur.x & 0x1FFFF;
        uint2 g = h1b[(size_t)r * 4 + q];         // 8B: 4 bf16 feats
        acc.x += a * __uint_as_float(g.x << 16);
        acc.y += a * __uint_as_float(g.x & 0xFFFF0000u);
        acc.z += a * __uint_as_float(g.y << 16);
        acc.w += a * __uint_as_float(g.y & 0xFFFF0000u);
    }
    float dc = dinv[c];
    uint2 gc = h1b[(size_t)c * 4 + q];
    float hcv[4] = {__uint_as_float(gc.x << 16), __uint_as_float(gc.x & 0xFFFF0000u),
                    __uint_as_float(gc.y << 16), __uint_as_float(gc.y & 0xFFFF0000u)};
    float av[4] = {acc.x + hcv[0], acc.y + hcv[1], acc.z + hcv[2], acc.w + hcv[3]};
    int j0 = q << 2;
    float p0 = 0.f, p1 = 0.f;
#pragma unroll
    for (int j = 0; j < 4; j++) {
        float rv = fmaxf(dc * av[j] + sb1[j0 + j], 0.f);
        p0 += rv * sW2[(j0 + j) * C_DIM + 0];
        p1 += rv * sW2[(j0 + j) * C_DIM + 1];
    }
    p0 += __shfl_xor(p0, 1); p0 += __shfl_xor(p0, 2);
    p1 += __shfl_xor(p1, 1); p1 += __shfl_xor(p1, 2);
    if (q == 0) ((float2*)h2s)[c] = make_float2(dc * p0, dc * p1);
}

// ---------- layer 2: CSR register-accumulate + bias + log_softmax ----------
__global__ __launch_bounds__(256) void k_agg2(
    const int2* __restrict__ rp, const int2* __restrict__ ebuf,
    const float* __restrict__ h2s, const float* __restrict__ dinv,
    const float* __restrict__ b2, float* __restrict__ out)
{
    int c = blockIdx.x * 256 + threadIdx.x;
    if (c >= N_NODES) return;
    int2 seg = rp[c];
    int s = seg.x, n = seg.y;
    const float2* h22 = (const float2*)h2s;
    float a0 = 0.f, a1 = 0.f;
    int2 v;
    if (n > 0) v = ebuf[s];
    for (int i = 0; i < n; i++) {
        int2 cur = v;
        if (i + 1 < n) v = ebuf[s + i + 1];
        float a = __int_as_float(cur.y);
        float2 hv = h22[cur.x & 0x1FFFF];
        a0 += a * hv.x;
        a1 += a * hv.y;
    }
    float dc = dinv[c];
    float2 hc = h22[c];
    float l0 = dc * (a0 + hc.x) + b2[0];
    float l1 = dc * (a1 + hc.y) + b2[1];
    float m = fmaxf(l0, l1);
    float lse = m + logf(expf(l0 - m) + expf(l1 - m));
    ((float2*)out)[c] = make_float2(l0 - lse, l1 - lse);
}

extern "C" void kernel_launch(void* const* d_in, const int* in_sizes, int n_in,
                              void* d_out, int out_size, void* d_ws, size_t ws_size,
                              hipStream_t stream) {
    const float* x  = (const float*)d_in[0];
    const int*   ei = (const int*)d_in[1];     // [2, E]: row then col
    const float* w  = (const float*)d_in[2];
    const float* W1 = (const float*)d_in[3];
    const float* b1 = (const float*)d_in[4];
    const float* W2 = (const float*)d_in[5];
    const float* b2 = (const float*)d_in[6];
    float* out = (float*)d_out;

    const int* row = ei;
    const int* col = ei + N_EDGES;

    // workspace layout (64B-aligned offsets)
    char* ws = (char*)d_ws;
    int*   gcur = (int*)(ws + 0);                //     3,200 B
    int2*  rp   = (int2*)(ws + 3200);            //   800,000 B (start,count per node)
    float* dinv = (float*)(ws + 803200);         //   400,000 B
    uint4* h1b  = (uint4*)(ws + 1203200);        // 3,200,000 B (bf16 16/row = 32 B)
    float* h2s  = (float*)(ws + 4403200);        //   800,000 B
    int2*  ebuf = (int2*)(ws + 5203200);         //29,628,416 B (782*4736*8)
    // end: 34,831,616 B

    k_init <<<4, 256, 0, stream>>>(gcur);
    k_part <<<NCHUNK, 1024, 0, stream>>>(row, col, w, gcur, ebuf);
    k_sort <<<NBUCK, 1024, 0, stream>>>(gcur, ebuf, rp, dinv);
    k_xw1  <<<(N_NODES + 255) / 256, 256, 0, stream>>>(x, W1, dinv, h1b);
    k_agg1 <<<(4 * N_NODES + 255) / 256, 256, 0, stream>>>(rp, ebuf, (const uint2*)h1b, dinv, b1, W2, h2s);
    k_agg2 <<<(N_NODES + 255) / 256, 256, 0, stream>>>(rp, ebuf, h2s, dinv, b2, out);
}